// Round 1
// baseline (1735.753 us; speedup 1.0000x reference)
//
#include <hip/hip_runtime.h>
#include <cstdint>
#include <cstddef>

// Problem constants (fixed by reference): N=4096, S=31, C=512, H=8, D=64
#define N_ 4096
#define S_ 31
#define C_ 512
#define H_ 8
#define M_ (N_*S_)     // 126976 rows
#define SS_ (S_*S_)    // 961
#define NH_ (N_*H_)    // 32768

typedef unsigned short u16;
typedef __bf16 v8bf __attribute__((ext_vector_type(8)));
typedef float  v4f  __attribute__((ext_vector_type(4)));
typedef unsigned short v8u __attribute__((ext_vector_type(8)));

// Workspace layout (bytes). Requires ws_size >= ~263 MB.
//   0         : wq_bf,wk_bf,wv_bf,wo_bf  (4 x 262144 u16 = 2 MB)
//   2097152   : statsf, 5892 floats:
//               [0:512] sum  [512:1024] sumsq  [1024:1536] scale  [1536:2048] shift
//               [2048:3009] esum [3009:3970] esumsq [3970:4931] scale2 [4931:5892] shift2
//   2121728   : energy fp32 [N][H][961]  (125,960,192 B)
//   128081920 : Vt bf16 [N][H][64][32]   (134,217,728 B)
#define WS_STATS  2097152
#define WS_ENERGY 2121728
#define WS_VT     128081920

__device__ __forceinline__ u16 f2bf(float f) {
  union { float f; unsigned u; } v; v.f = f;
  unsigned r = v.u + 0x7FFFu + ((v.u >> 16) & 1u);
  return (u16)(r >> 16);
}

// ---------------- Kernel 0: convert weights to bf16 + zero stat accumulators
__global__ void k_init(const float* wq, const float* wk, const float* wv, const float* wo,
                       u16* wbf, float* statsf) {
  int gid = blockIdx.x * 256 + threadIdx.x;   // grid covers 4*262144 exactly
  if (gid < 5892) statsf[gid] = 0.0f;
  int m = gid >> 18;
  int rem = gid & 262143;
  const float* src = (m == 0) ? wq : (m == 1) ? wk : (m == 2) ? wv : wo;
  wbf[(size_t)m * 262144 + rem] = f2bf(src[rem]);
}

// ---------------- Kernel 1: per-channel sum/sumsq of x over all M rows
__global__ void __launch_bounds__(512) k_xstats(const float* __restrict__ x, float* statsf) {
  int c = threadIdx.x;                 // 512 channels
  int r0 = blockIdx.x * 512;           // 248 blocks * 512 rows = 126976
  float s = 0.f, sq = 0.f;
  const float* p = x + (size_t)r0 * C_ + c;
  for (int i = 0; i < 512; ++i) { float v = p[(size_t)i * C_]; s += v; sq += v * v; }
  atomicAdd(&statsf[c], s);
  atomicAdd(&statsf[512 + c], sq);
}

// ---------------- Kernel 1b: finalize channel scale/shift
__global__ void k_finalize_ch(const float* gamma, const float* beta, float* statsf) {
  int c = threadIdx.x;                 // 512
  float mu  = statsf[c] * (1.0f / (float)M_);
  float var = statsf[512 + c] * (1.0f / (float)M_) - mu * mu;
  float sc  = rsqrtf(var + 1e-5f) * gamma[c];
  statsf[1024 + c] = sc;
  statsf[1536 + c] = beta[c] - mu * sc;
}

// ---------------- Kernel 2: per-n fused  normalize -> Q,K,V GEMM -> energy + Vt
__global__ void __launch_bounds__(512, 4)
k_main(const float* __restrict__ x, const u16* __restrict__ wbf,
       const float* __restrict__ statsf, float* __restrict__ energy, u16* __restrict__ vt) {
  __shared__ float s_scale[C_], s_shift[C_];
  __shared__ u16 s_xn[32 * 520];        // normalized x, bf16, pitch 520 (bank-friendly)
  __shared__ u16 s_q[2][32 * 72];       // per-head-pair Q (pitch 72)
  __shared__ u16 s_k[2][32 * 72];
  __shared__ u16 s_v[2][32 * 72];
  // total LDS = 4096 + 33280 + 3*2*4608 = 65024 B (<= 64 KB)

  int n = blockIdx.x, t = threadIdx.x;
  int wave = t >> 6, lane = t & 63, l15 = lane & 15, quad = lane >> 4;

  if (t < 512) { s_scale[t] = statsf[1024 + t]; s_shift[t] = statsf[1536 + t]; }
  __syncthreads();

  // ---- stage normalized x (31 rows) into LDS as bf16
  const float* xb = x + (size_t)n * (S_ * C_);
  for (int idx = t; idx < 31 * 64; idx += 512) {
    int row = idx >> 6, c8 = (idx & 63) << 3;
    const float* g = xb + row * C_ + c8;
    float4 a = *(const float4*)g;
    float4 b = *(const float4*)(g + 4);
    v8u o;
    o[0] = f2bf(a.x * s_scale[c8 + 0] + s_shift[c8 + 0]);
    o[1] = f2bf(a.y * s_scale[c8 + 1] + s_shift[c8 + 1]);
    o[2] = f2bf(a.z * s_scale[c8 + 2] + s_shift[c8 + 2]);
    o[3] = f2bf(a.w * s_scale[c8 + 3] + s_shift[c8 + 3]);
    o[4] = f2bf(b.x * s_scale[c8 + 4] + s_shift[c8 + 4]);
    o[5] = f2bf(b.y * s_scale[c8 + 5] + s_shift[c8 + 5]);
    o[6] = f2bf(b.z * s_scale[c8 + 6] + s_shift[c8 + 6]);
    o[7] = f2bf(b.w * s_scale[c8 + 7] + s_shift[c8 + 7]);
    *(v8u*)(s_xn + row * 520 + c8) = o;
  }
  if (t < 64) {                          // zero pad row 31
    v8u z = {0,0,0,0,0,0,0,0};
    *(v8u*)(s_xn + 31 * 520 + t * 8) = z;
  }
  __syncthreads();

  const u16* Wmats[3] = { wbf, wbf + 262144, wbf + 524288 };

  #pragma unroll 1
  for (int hp = 0; hp < 4; ++hp) {       // head pairs (heads 2hp, 2hp+1 = cols hp*128..)
    // ---- phase C: Q,K,V for the two heads. 24 items = (mat 0..2) x (nt 0..7)
    #pragma unroll 1
    for (int i = 0; i < 3; ++i) {
      int item = wave * 3 + i;
      int mat = item >> 3, nt = item & 7;
      int col0 = hp * 128 + nt * 16;
      const u16* W  = Wmats[mat] + ((size_t)(col0 + l15) * C_ + quad * 8);
      const u16* A0 = s_xn + (l15 * 520 + quad * 8);
      const u16* A1 = s_xn + ((16 + l15) * 520 + quad * 8);
      v4f acc0 = {0,0,0,0}, acc1 = {0,0,0,0};
      #pragma unroll 4
      for (int kk = 0; kk < 16; ++kk) {
        v8bf b  = *(const v8bf*)(W  + kk * 32);
        v8bf a0 = *(const v8bf*)(A0 + kk * 32);
        v8bf a1 = *(const v8bf*)(A1 + kk * 32);
        acc0 = __builtin_amdgcn_mfma_f32_16x16x32_bf16(a0, b, acc0, 0, 0, 0);
        acc1 = __builtin_amdgcn_mfma_f32_16x16x32_bf16(a1, b, acc1, 0, 0, 0);
      }
      int hh = nt >> 2, cc0 = (nt & 3) * 16;
      u16* dst = (mat == 0) ? s_q[hh] : (mat == 1) ? s_k[hh] : s_v[hh];
      #pragma unroll
      for (int reg = 0; reg < 4; ++reg) {
        int rm = quad * 4 + reg;
        dst[rm * 72 + cc0 + l15]        = f2bf(acc0[reg]);
        dst[(16 + rm) * 72 + cc0 + l15] = f2bf(acc1[reg]);
      }
    }
    __syncthreads();

    // ---- phase D: energy = Q_h K_h^T  (8 tiles, one per wave)
    {
      int hh = wave >> 2, qt = (wave >> 1) & 1, kt = wave & 1;
      v4f acc = {0,0,0,0};
      #pragma unroll
      for (int kk = 0; kk < 2; ++kk) {
        v8bf a = *(const v8bf*)(s_q[hh] + (qt * 16 + l15) * 72 + kk * 32 + quad * 8);
        v8bf b = *(const v8bf*)(s_k[hh] + (kt * 16 + l15) * 72 + kk * 32 + quad * 8);
        acc = __builtin_amdgcn_mfma_f32_16x16x32_bf16(a, b, acc, 0, 0, 0);
      }
      float* eg = energy + ((size_t)n * H_ + hp * 2 + hh) * SS_;
      int k = kt * 16 + l15;
      if (k < 31) {
        #pragma unroll
        for (int reg = 0; reg < 4; ++reg) {
          int q = qt * 16 + quad * 4 + reg;
          if (q < 31) eg[q * 31 + k] = acc[reg];
        }
      }
    }

    // ---- phase E: write V transposed -> Vt[n][h][c][l] (bf16, l padded to 32)
    if (t < 128) {
      int hh = t >> 6, c = t & 63;
      u16* dst = vt + (((size_t)n * H_ + hp * 2 + hh) * 64 + c) * 32;
      #pragma unroll
      for (int g = 0; g < 4; ++g) {
        v8u o;
        #pragma unroll
        for (int j = 0; j < 8; ++j) o[j] = s_v[hh][(g * 8 + j) * 72 + c];
        *(v8u*)(dst + g * 8) = o;
      }
    }
    __syncthreads();
  }
}

// ---------------- Kernel 3: energy per-SS-channel sum/sumsq over (n,h)
__global__ void __launch_bounds__(256) k_estats(const float* __restrict__ energy, float* statsf) {
  int t = threadIdx.x;                 // 256
  int r0 = blockIdx.x * 128;           // 256 blocks * 128 rows = 32768
  float s[4] = {0,0,0,0}, sq[4] = {0,0,0,0};
  for (int i = 0; i < 128; ++i) {
    const float* row = energy + (size_t)(r0 + i) * SS_;
    #pragma unroll
    for (int j = 0; j < 4; ++j) {
      int c = t + j * 256;
      if (c < SS_) { float v = row[c]; s[j] += v; sq[j] += v * v; }
    }
  }
  #pragma unroll
  for (int j = 0; j < 4; ++j) {
    int c = t + j * 256;
    if (c < SS_) { atomicAdd(&statsf[2048 + c], s[j]); atomicAdd(&statsf[3009 + c], sq[j]); }
  }
}

// ---------------- Kernel 3b: finalize SS-channel scale2/shift2
__global__ void k_finalize_e(const float* pg, const float* pb, float* statsf) {
  int c = threadIdx.x;                 // 1024 threads
  if (c >= SS_) return;
  float mu  = statsf[2048 + c] * (1.0f / (float)NH_);
  float var = statsf[3009 + c] * (1.0f / (float)NH_) - mu * mu;
  float sc  = rsqrtf(var + 1e-5f) * pg[c];
  statsf[3970 + c] = sc;
  statsf[4931 + c] = pb[c] - mu * sc;
}

// ---------------- Kernel 4: per-n  norm -> softmax -> A*V -> O-proj -> +x
__global__ void __launch_bounds__(512, 4)
k_attn(const float* __restrict__ x, const u16* __restrict__ wbf,
       const float* __restrict__ statsf, const float* __restrict__ energy,
       const u16* __restrict__ vt, const float* __restrict__ bo, float* __restrict__ out) {
  __shared__ float s_s2[SS_], s_sh2[SS_];
  __shared__ float s_logit[32 * 33];    // pitch 33 -> conflict-free row reads
  __shared__ u16  s_attn[32 * 40];      // bf16, pitch 40 (80B, 16B-aligned rows)
  __shared__ u16  s_vt[64 * 32];        // Vt for one head
  __shared__ u16  s_out[32 * 520];      // attention output (bf16), pitch 520
  // total LDS = 7688 + 4224 + 2560 + 4096 + 33280 = 51848 B

  int n = blockIdx.x, t = threadIdx.x;
  int wave = t >> 6, lane = t & 63, l15 = lane & 15, quad = lane >> 4;
  const float inv_sqrt_c = 0.04419417382415922f;   // 1/sqrt(512)

  for (int idx = t; idx < SS_; idx += 512) {
    s_s2[idx]  = statsf[3970 + idx];
    s_sh2[idx] = statsf[4931 + idx];
  }

  #pragma unroll 1
  for (int h = 0; h < H_; ++h) {
    __syncthreads();   // also orders the s_s2 load before first use
    const float* eg = energy + ((size_t)n * H_ + h) * SS_;
    for (int idx = t; idx < SS_; idx += 512) {
      int q = idx / 31, k = idx - q * 31;
      s_logit[q * 33 + k] = (eg[idx] * s_s2[idx] + s_sh2[idx]) * inv_sqrt_c;
    }
    if (t < 256) {
      ((uint4*)s_vt)[t] = ((const uint4*)(vt + ((size_t)n * H_ + h) * 2048))[t];
    }
    __syncthreads();

    // softmax over k (rows q=0..30), write bf16 attn with padded row/col 31 = 0
    if (t < 31) {
      float mx = -1e30f;
      #pragma unroll
      for (int k = 0; k < 31; ++k) mx = fmaxf(mx, s_logit[t * 33 + k]);
      float sum = 0.f;
      #pragma unroll
      for (int k = 0; k < 31; ++k) {
        float e = __expf(s_logit[t * 33 + k] - mx);
        s_logit[t * 33 + k] = e;
        sum += e;
      }
      float r = 1.0f / sum;
      #pragma unroll
      for (int k = 0; k < 31; ++k) s_attn[t * 40 + k] = f2bf(s_logit[t * 33 + k] * r);
      s_attn[t * 40 + 31] = 0;
    } else if (t == 31) {
      #pragma unroll
      for (int k = 0; k < 32; ++k) s_attn[31 * 40 + k] = 0;
    }
    __syncthreads();

    // A*V: 8 tiles (ct 0..3, mt 0..1), one per wave, single 16x16x32 MFMA
    {
      int ct = wave & 3, mt = wave >> 2;
      v8bf a = *(const v8bf*)(s_attn + (mt * 16 + l15) * 40 + quad * 8);
      v8bf b = *(const v8bf*)(s_vt + (ct * 16 + l15) * 32 + quad * 8);
      v4f acc = {0,0,0,0};
      acc = __builtin_amdgcn_mfma_f32_16x16x32_bf16(a, b, acc, 0, 0, 0);
      #pragma unroll
      for (int reg = 0; reg < 4; ++reg) {
        int rm = mt * 16 + quad * 4 + reg;
        s_out[rm * 520 + h * 64 + ct * 16 + l15] = f2bf(acc[reg]);
      }
    }
  }
  __syncthreads();

  // O-projection + bias + residual
  const u16* Wo = wbf + 786432;
  const float* xb = x + (size_t)n * (S_ * C_);
  float* ob = out + (size_t)n * (S_ * C_);
  #pragma unroll 1
  for (int i = 0; i < 4; ++i) {
    int nt = wave + i * 8;
    int j = nt * 16 + l15;
    const u16* W  = Wo + ((size_t)j * C_ + quad * 8);
    const u16* A0 = s_out + (l15 * 520 + quad * 8);
    const u16* A1 = s_out + ((16 + l15) * 520 + quad * 8);
    v4f acc0 = {0,0,0,0}, acc1 = {0,0,0,0};
    #pragma unroll 4
    for (int kk = 0; kk < 16; ++kk) {
      v8bf b  = *(const v8bf*)(W  + kk * 32);
      v8bf a0 = *(const v8bf*)(A0 + kk * 32);
      v8bf a1 = *(const v8bf*)(A1 + kk * 32);
      acc0 = __builtin_amdgcn_mfma_f32_16x16x32_bf16(a0, b, acc0, 0, 0, 0);
      acc1 = __builtin_amdgcn_mfma_f32_16x16x32_bf16(a1, b, acc1, 0, 0, 0);
    }
    float bj = bo[j];
    #pragma unroll
    for (int reg = 0; reg < 4; ++reg) {
      int q = quad * 4 + reg;
      ob[q * C_ + j] = acc0[reg] + bj + xb[q * C_ + j];
      int q2 = 16 + q;
      if (q2 < 31) ob[q2 * C_ + j] = acc1[reg] + bj + xb[q2 * C_ + j];
    }
  }
}

extern "C" void kernel_launch(void* const* d_in, const int* in_sizes, int n_in,
                              void* d_out, int out_size, void* d_ws, size_t ws_size,
                              hipStream_t stream) {
  const float* x     = (const float*)d_in[0];
  const float* gamma = (const float*)d_in[1];
  const float* beta  = (const float*)d_in[2];
  const float* wq    = (const float*)d_in[3];
  const float* wk    = (const float*)d_in[4];
  const float* wv    = (const float*)d_in[5];
  const float* wo    = (const float*)d_in[6];
  const float* bo    = (const float*)d_in[7];
  const float* pg    = (const float*)d_in[8];
  const float* pb    = (const float*)d_in[9];

  char* ws = (char*)d_ws;
  u16*   wbf    = (u16*)ws;
  float* statsf = (float*)(ws + WS_STATS);
  float* energy = (float*)(ws + WS_ENERGY);
  u16*   vtp    = (u16*)(ws + WS_VT);
  float* outp   = (float*)d_out;

  k_init<<<4096, 256, 0, stream>>>(wq, wk, wv, wo, wbf, statsf);
  k_xstats<<<248, 512, 0, stream>>>(x, statsf);
  k_finalize_ch<<<1, 512, 0, stream>>>(gamma, beta, statsf);
  k_main<<<4096, 512, 0, stream>>>(x, wbf, statsf, energy, vtp);
  k_estats<<<256, 256, 0, stream>>>(energy, statsf);
  k_finalize_e<<<1, 1024, 0, stream>>>(pg, pb, statsf);
  k_attn<<<4096, 512, 0, stream>>>(x, wbf, statsf, energy, vtp, bo, outp);
}

// Round 2
// 1243.485 us; speedup vs baseline: 1.3959x; 1.3959x over previous
//
#include <hip/hip_runtime.h>
#include <cstdint>
#include <cstddef>

// Problem constants: N=4096, S=31, C=512, H=8, D=64
#define N_ 4096
#define S_ 31
#define C_ 512
#define H_ 8
#define M_ (N_*S_)     // 126976
#define NH_ (N_*H_)    // 32768

typedef unsigned short u16;
typedef unsigned char  u8;
typedef __bf16 v8bf __attribute__((ext_vector_type(8)));
typedef float  v4f  __attribute__((ext_vector_type(4)));
typedef float  v2f  __attribute__((ext_vector_type(2)));
typedef unsigned short v8u __attribute__((ext_vector_type(8)));

// Workspace layout (bytes), total ~203.5 MB (< proven 262 MB budget):
//   0        : wbf  bf16 [2048 cols][512] = wq,wk,wv,wo concatenated (2 MB)
//   2 MB     : statsf, 6144 f32:
//     [0:512] xsum [512:1024] xsumsq [1024:1536] scale [1536:2048] shift
//     [2048:3072] esum(padded1024) [3072:4096] esumsq [4096:5120] s2p [5120:6144] sh2p
//   WS_Q : Qg fp8 [n][h][32][64]  (67 MB)  -- energy bf16 [nh][32][32] ALIASES this
//   WS_K : Kg fp8 [n][h][32][64]  (67 MB)
//   WS_V : Vt fp8 [n][h][64][32]  (67 MB)
#define WS_STATS 2097152
#define WS_Q (WS_STATS + 32768)
#define WS_K (WS_Q + 67108864)
#define WS_V (WS_K + 67108864)

#define SCALE_QK 16.0f
#define SCALE_V  16.0f

__device__ __forceinline__ u16 f2bf(float f) {
  union { float f; unsigned u; } v; v.f = f;
  unsigned r = v.u + 0x7FFFu + ((v.u >> 16) & 1u);
  return (u16)(r >> 16);
}
__device__ __forceinline__ float bf2f(u16 v) {
  union { unsigned u; float f; } w; w.u = ((unsigned)v) << 16; return w.f;
}
__device__ __forceinline__ u8 enc1(float f) {
  return (u8)(__builtin_amdgcn_cvt_pk_fp8_f32(f, f, 0, false) & 0xff);
}
__device__ __forceinline__ unsigned enc4(float a, float b, float c, float d) {
  int w = __builtin_amdgcn_cvt_pk_fp8_f32(a, b, 0, false);
  w = __builtin_amdgcn_cvt_pk_fp8_f32(c, d, w, true);
  return (unsigned)w;
}
__device__ __forceinline__ v8bf dec8(uint2 u) {
  v2f p0 = __builtin_amdgcn_cvt_pk_f32_fp8((int)u.x, false);
  v2f p1 = __builtin_amdgcn_cvt_pk_f32_fp8((int)u.x, true);
  v2f p2 = __builtin_amdgcn_cvt_pk_f32_fp8((int)u.y, false);
  v2f p3 = __builtin_amdgcn_cvt_pk_f32_fp8((int)u.y, true);
  v8bf r;
  r[0]=(__bf16)p0[0]; r[1]=(__bf16)p0[1]; r[2]=(__bf16)p1[0]; r[3]=(__bf16)p1[1];
  r[4]=(__bf16)p2[0]; r[5]=(__bf16)p2[1]; r[6]=(__bf16)p3[0]; r[7]=(__bf16)p3[1];
  return r;
}

// ---------------- K0: weights fp32 -> bf16 [2048][512]; zero stat accumulators
__global__ void k_init(const float* wq, const float* wk, const float* wv, const float* wo,
                       u16* wbf, float* statsf) {
  int gid = blockIdx.x * 256 + threadIdx.x;   // 4096*256 = 1048576 = 4*262144
  if (gid < 6144) statsf[gid] = 0.0f;
  int m = gid >> 18, rem = gid & 262143;
  const float* src = (m == 0) ? wq : (m == 1) ? wk : (m == 2) ? wv : wo;
  wbf[(size_t)m * 262144 + rem] = f2bf(src[rem]);
}

// ---------------- K1: per-channel sum/sumsq of x (float4 loads)
__global__ void __launch_bounds__(512) k_xstats(const float* __restrict__ x, float* statsf) {
  int t = threadIdx.x;
  int c4 = (t & 127) * 4;
  int r0 = blockIdx.x * 512 + (t >> 7) * 128;
  float4 s = {0,0,0,0}, sq = {0,0,0,0};
  const float* p = x + (size_t)r0 * C_ + c4;
  for (int i = 0; i < 128; ++i) {
    float4 v = *(const float4*)(p + (size_t)i * C_);
    s.x += v.x; s.y += v.y; s.z += v.z; s.w += v.w;
    sq.x += v.x*v.x; sq.y += v.y*v.y; sq.z += v.z*v.z; sq.w += v.w*v.w;
  }
  atomicAdd(&statsf[c4+0], s.x); atomicAdd(&statsf[c4+1], s.y);
  atomicAdd(&statsf[c4+2], s.z); atomicAdd(&statsf[c4+3], s.w);
  atomicAdd(&statsf[512+c4+0], sq.x); atomicAdd(&statsf[512+c4+1], sq.y);
  atomicAdd(&statsf[512+c4+2], sq.z); atomicAdd(&statsf[512+c4+3], sq.w);
}

__global__ void k_finalize_ch(const float* gamma, const float* beta, float* statsf) {
  int c = threadIdx.x;
  float mu  = statsf[c] * (1.0f / (float)M_);
  float var = statsf[512 + c] * (1.0f / (float)M_) - mu * mu;
  float sc  = rsqrtf(var + 1e-5f) * gamma[c];
  statsf[1024 + c] = sc;
  statsf[1536 + c] = beta[c] - mu * sc;
}

// ---------------- K2: normalize -> QKV GEMM (A persistent LDS, B streamed from L2)
// Block = 4 batch items (128 padded rows), 512 thr. Wave grid 2x4, wave tile 64x64.
__global__ void __launch_bounds__(512, 2)
k_qkv(const float* __restrict__ x, const u16* __restrict__ wbf,
      const float* __restrict__ statsf, u8* __restrict__ qg, u8* __restrict__ kg,
      u8* __restrict__ vt) {
  __shared__ float s_scale[C_], s_shift[C_];
  __shared__ u16 s_a[16*8*64*8];   // [kk][mt][slot][8] fragment order, 128 KB
  int t = threadIdx.x, nblk = blockIdx.x;
  int wave = t >> 6, lane = t & 63, l15 = lane & 15, quad = lane >> 4;
  if (t < 512) { s_scale[t] = statsf[1024+t]; s_shift[t] = statsf[1536+t]; }
  __syncthreads();

  // stage normalized A in fragment order (row 31 of each n zeroed)
  const float* xb = x + (size_t)nblk * 4 * S_ * C_;
  for (int it = 0; it < 16; ++it) {
    int idx = t + it * 512;
    int row = idx >> 6, c8 = (idx & 63) << 3;
    int nl = row >> 5, s = row & 31;
    int kk = c8 >> 5, q4 = (c8 >> 3) & 3, mt = row >> 4, r15 = row & 15;
    u16* dst = s_a + ((((kk*8 + mt) << 6) | (q4*16 + r15)) << 3);
    v8u o;
    if (s == 31) { o = (v8u){0,0,0,0,0,0,0,0}; }
    else {
      const float* g = xb + (size_t)(nl * 31 + s) * C_ + c8;
      float4 a = *(const float4*)g, b = *(const float4*)(g + 4);
      o[0]=f2bf(a.x*s_scale[c8+0]+s_shift[c8+0]); o[1]=f2bf(a.y*s_scale[c8+1]+s_shift[c8+1]);
      o[2]=f2bf(a.z*s_scale[c8+2]+s_shift[c8+2]); o[3]=f2bf(a.w*s_scale[c8+3]+s_shift[c8+3]);
      o[4]=f2bf(b.x*s_scale[c8+4]+s_shift[c8+4]); o[5]=f2bf(b.y*s_scale[c8+5]+s_shift[c8+5]);
      o[6]=f2bf(b.z*s_scale[c8+6]+s_shift[c8+6]); o[7]=f2bf(b.w*s_scale[c8+7]+s_shift[c8+7]);
    }
    *(v8u*)dst = o;
  }
  __syncthreads();

  int wr = wave >> 2, wc = wave & 3;
  #pragma unroll 1
  for (int ci = 0; ci < 6; ++ci) {
    int jb = ci * 256 + wc * 64;
    const u16* B0 = wbf + (size_t)(jb + l15) * 512 + quad * 8;
    v4f acc[4][4];
    #pragma unroll
    for (int m = 0; m < 4; ++m)
      #pragma unroll
      for (int c = 0; c < 4; ++c) acc[m][c] = (v4f){0,0,0,0};

    #pragma unroll 2
    for (int kk = 0; kk < 16; ++kk) {
      v8bf a[4], b[4];
      #pragma unroll
      for (int m = 0; m < 4; ++m)
        a[m] = *(const v8bf*)(s_a + ((((kk*8 + wr*4 + m) << 6) | lane) << 3));
      #pragma unroll
      for (int c = 0; c < 4; ++c)
        b[c] = *(const v8bf*)(B0 + (size_t)c * 16 * 512 + kk * 32);
      #pragma unroll
      for (int m = 0; m < 4; ++m)
        #pragma unroll
        for (int c = 0; c < 4; ++c)
          acc[m][c] = __builtin_amdgcn_mfma_f32_16x16x32_bf16(a[m], b[c], acc[m][c], 0, 0, 0);
    }

    // epilogue: write Q/K (fp8, [n][h][32s][64d]) or Vt (fp8, [n][h][64d][32s])
    #pragma unroll
    for (int m = 0; m < 4; ++m) {
      int rbase = wr*64 + m*16 + quad*4;
      int nl = rbase >> 5, s0 = rbase & 31;
      size_t nbase = (size_t)(nblk*4 + nl) * 8;
      #pragma unroll
      for (int c = 0; c < 4; ++c) {
        int j = jb + c*16 + l15;
        int mat = j >> 9, jj = j & 511, h = jj >> 6, d = jj & 63;
        if (mat == 2) {
          unsigned w = enc4(acc[m][c][0]*SCALE_V, acc[m][c][1]*SCALE_V,
                            acc[m][c][2]*SCALE_V, acc[m][c][3]*SCALE_V);
          *(unsigned*)(vt + ((nbase + h) * 2048) + d*32 + s0) = w;
        } else {
          u8* dst = ((mat == 0) ? qg : kg) + (nbase + h) * 2048 + (size_t)s0 * 64 + d;
          #pragma unroll
          for (int reg = 0; reg < 4; ++reg)
            dst[reg * 64] = enc1(acc[m][c][reg] * SCALE_QK);
        }
      }
    }
  }
}

// ---------------- K3: energy = Q K^T per (n,h); writes bf16 [32][32] ALIASED over Qg tile
__global__ void __launch_bounds__(512)
k_energy(u8* __restrict__ qg, const u8* __restrict__ kg) {
  int t = threadIdx.x;
  int wave = t >> 6, lane = t & 63, l15 = lane & 15, quad = lane >> 4;
  size_t nh = (size_t)blockIdx.x * 8 + wave;
  const u8* qp = qg + nh * 2048;
  const u8* kp = kg + nh * 2048;
  v8bf A[2][2], B[2][2];
  #pragma unroll
  for (int mt = 0; mt < 2; ++mt)
    #pragma unroll
    for (int kk = 0; kk < 2; ++kk) {
      A[mt][kk] = dec8(*(const uint2*)(qp + (mt*16 + l15)*64 + kk*32 + quad*8));
      B[mt][kk] = dec8(*(const uint2*)(kp + (mt*16 + l15)*64 + kk*32 + quad*8));
    }
  v4f acc[2][2];
  #pragma unroll
  for (int qt = 0; qt < 2; ++qt)
    #pragma unroll
    for (int kt = 0; kt < 2; ++kt) {
      v4f a = {0,0,0,0};
      a = __builtin_amdgcn_mfma_f32_16x16x32_bf16(A[qt][0], B[kt][0], a, 0, 0, 0);
      a = __builtin_amdgcn_mfma_f32_16x16x32_bf16(A[qt][1], B[kt][1], a, 0, 0, 0);
      acc[qt][kt] = a;
    }
  u16* ep = (u16*)(qg + nh * 2048);
  const float inv = 1.0f / (SCALE_QK * SCALE_QK);
  #pragma unroll
  for (int qt = 0; qt < 2; ++qt)
    #pragma unroll
    for (int kt = 0; kt < 2; ++kt) {
      int k = kt*16 + l15;
      #pragma unroll
      for (int reg = 0; reg < 4; ++reg) {
        int q = qt*16 + quad*4 + reg;
        ep[q*32 + k] = f2bf(acc[qt][kt][reg] * inv);
      }
    }
}

// ---------------- K4: energy per-padded-channel sum/sumsq over (n,h)
__global__ void __launch_bounds__(256) k_estats(const u16* __restrict__ eg, float* statsf) {
  int t = threadIdx.x;
  int r0 = blockIdx.x * 128;
  float s[4] = {0,0,0,0}, sq[4] = {0,0,0,0};
  for (int i = 0; i < 128; ++i) {
    uint2 u = *(const uint2*)(eg + (size_t)(r0 + i) * 1024 + t * 4);
    float v0 = bf2f((u16)(u.x & 0xffff)), v1 = bf2f((u16)(u.x >> 16));
    float v2 = bf2f((u16)(u.y & 0xffff)), v3 = bf2f((u16)(u.y >> 16));
    s[0]+=v0; s[1]+=v1; s[2]+=v2; s[3]+=v3;
    sq[0]+=v0*v0; sq[1]+=v1*v1; sq[2]+=v2*v2; sq[3]+=v3*v3;
  }
  #pragma unroll
  for (int j = 0; j < 4; ++j) {
    atomicAdd(&statsf[2048 + t*4 + j], s[j]);
    atomicAdd(&statsf[3072 + t*4 + j], sq[j]);
  }
}

__global__ void k_finalize_e(const float* pg, const float* pb, float* statsf) {
  int c = threadIdx.x;       // 1024
  int q = c >> 5, k = c & 31;
  const float invC = 0.04419417382415922f;   // 1/sqrt(512)
  float s2 = 0.f, sh2 = 0.f;
  if (q < 31 && k < 31) {
    int ss = q*31 + k;
    float mu  = statsf[2048 + c] * (1.0f / (float)NH_);
    float var = statsf[3072 + c] * (1.0f / (float)NH_) - mu * mu;
    float sc  = rsqrtf(var + 1e-5f) * pg[ss];
    s2  = sc * invC;
    sh2 = (pb[ss] - mu * sc) * invC;
  }
  statsf[4096 + c] = s2;
  statsf[5120 + c] = sh2;
}

// ---------------- K5: softmax + A*V -> LDS A, then O-proj GEMM + bias + residual
__global__ void __launch_bounds__(512, 2)
k_oproj(const float* __restrict__ x, const u16* __restrict__ wbf,
        const float* __restrict__ statsf, const u16* __restrict__ eg,
        const u8* __restrict__ vt, const float* __restrict__ bo, float* __restrict__ out) {
  __shared__ u16 s_a[16*8*64*8];        // 128 KB, fragment order
  __shared__ float s_s2[1024], s_sh2[1024];
  __shared__ u16 s_attn[8][1024];       // per-wave [32 q][32 k] bf16
  int t = threadIdx.x, nblk = blockIdx.x;
  int wave = t >> 6, lane = t & 63, l15 = lane & 15, quad = lane >> 4;
  for (int i = t; i < 1024; i += 512) { s_s2[i] = statsf[4096+i]; s_sh2[i] = statsf[5120+i]; }
  __syncthreads();

  // phase 1: 32 tasks = 4n x 8h; wave handles 4
  int q = lane & 31, half = lane >> 5;
  #pragma unroll 1
  for (int tk = 0; tk < 4; ++tk) {
    int task = wave * 4 + tk;
    int nl = task >> 3, h = task & 7;
    size_t nh = (size_t)(nblk*4 + nl) * 8 + h;
    const u16* ep = eg + nh * 1024;
    int cb = q*32 + half*16;
    v8u e0 = *(const v8u*)(ep + cb);
    v8u e1 = *(const v8u*)(ep + cb + 8);
    float lg[16];
    #pragma unroll
    for (int j = 0; j < 8; ++j) lg[j]   = bf2f(e0[j]) * s_s2[cb+j]   + s_sh2[cb+j];
    #pragma unroll
    for (int j = 0; j < 8; ++j) lg[8+j] = bf2f(e1[j]) * s_s2[cb+8+j] + s_sh2[cb+8+j];
    if (half) lg[15] = -1e30f;            // k=31 pad excluded
    float mx = lg[0];
    #pragma unroll
    for (int j = 1; j < 16; ++j) mx = fmaxf(mx, lg[j]);
    mx = fmaxf(mx, __shfl_xor(mx, 32));
    float sum = 0.f;
    #pragma unroll
    for (int j = 0; j < 16; ++j) { lg[j] = __expf(lg[j] - mx); sum += lg[j]; }
    sum += __shfl_xor(sum, 32);
    float r = (q == 31) ? 0.f : (1.0f / sum);
    v8u o0, o1;
    #pragma unroll
    for (int j = 0; j < 8; ++j) { o0[j] = f2bf(lg[j] * r); o1[j] = f2bf(lg[8+j] * r); }
    *(v8u*)(&s_attn[wave][cb]) = o0;
    *(v8u*)(&s_attn[wave][cb + 8]) = o1;
    // A*V for this (n,h)
    v8bf a0 = *(const v8bf*)(&s_attn[wave][(l15)*32 + quad*8]);
    v8bf a1 = *(const v8bf*)(&s_attn[wave][(16 + l15)*32 + quad*8]);
    const float invV = 1.0f / SCALE_V;
    #pragma unroll
    for (int ct = 0; ct < 4; ++ct) {
      uint2 u = *(const uint2*)(vt + nh*2048 + (ct*16 + l15)*32 + quad*8);
      v8bf b = dec8(u);
      v4f c0 = {0,0,0,0}, c1 = {0,0,0,0};
      c0 = __builtin_amdgcn_mfma_f32_16x16x32_bf16(a0, b, c0, 0, 0, 0);
      c1 = __builtin_amdgcn_mfma_f32_16x16x32_bf16(a1, b, c1, 0, 0, 0);
      int ch = h*64 + ct*16 + l15;
      int kkA = ch >> 5, qA = (ch >> 3) & 3, pA = ch & 7;
      #pragma unroll
      for (int reg = 0; reg < 4; ++reg) {
        int rm = quad*4 + reg;
        s_a[((((kkA*8 + nl*2 + 0) << 6) | (qA*16 + rm)) << 3) + pA] = f2bf(c0[reg] * invV);
        s_a[((((kkA*8 + nl*2 + 1) << 6) | (qA*16 + rm)) << 3) + pA] = f2bf(c1[reg] * invV);
      }
    }
  }
  __syncthreads();

  // phase 2: O-proj GEMM (cols 512 = mat 3 of wbf), bias + residual, fp32 out
  int wr = wave >> 2, wc = wave & 3;
  #pragma unroll 1
  for (int ci = 0; ci < 2; ++ci) {
    int jb = ci * 256 + wc * 64;
    const u16* B0 = wbf + (size_t)(1536 + jb + l15) * 512 + quad * 8;
    v4f acc[4][4];
    #pragma unroll
    for (int m = 0; m < 4; ++m)
      #pragma unroll
      for (int c = 0; c < 4; ++c) acc[m][c] = (v4f){0,0,0,0};
    #pragma unroll 2
    for (int kk = 0; kk < 16; ++kk) {
      v8bf a[4], b[4];
      #pragma unroll
      for (int m = 0; m < 4; ++m)
        a[m] = *(const v8bf*)(s_a + ((((kk*8 + wr*4 + m) << 6) | lane) << 3));
      #pragma unroll
      for (int c = 0; c < 4; ++c)
        b[c] = *(const v8bf*)(B0 + (size_t)c * 16 * 512 + kk * 32);
      #pragma unroll
      for (int m = 0; m < 4; ++m)
        #pragma unroll
        for (int c = 0; c < 4; ++c)
          acc[m][c] = __builtin_amdgcn_mfma_f32_16x16x32_bf16(a[m], b[c], acc[m][c], 0, 0, 0);
    }
    #pragma unroll
    for (int m = 0; m < 4; ++m) {
      int rbase = wr*64 + m*16 + quad*4;
      int nl = rbase >> 5, s0 = rbase & 31;
      #pragma unroll
      for (int c = 0; c < 4; ++c) {
        int j = jb + c*16 + l15;
        float bj = bo[j];
        #pragma unroll
        for (int reg = 0; reg < 4; ++reg) {
          int s = s0 + reg;
          if (s < 31) {
            size_t off = (size_t)((nblk*4 + nl) * 31 + s) * C_ + j;
            out[off] = acc[m][c][reg] + bj + x[off];
          }
        }
      }
    }
  }
}

extern "C" void kernel_launch(void* const* d_in, const int* in_sizes, int n_in,
                              void* d_out, int out_size, void* d_ws, size_t ws_size,
                              hipStream_t stream) {
  const float* x     = (const float*)d_in[0];
  const float* gamma = (const float*)d_in[1];
  const float* beta  = (const float*)d_in[2];
  const float* wq    = (const float*)d_in[3];
  const float* wk    = (const float*)d_in[4];
  const float* wv    = (const float*)d_in[5];
  const float* wo    = (const float*)d_in[6];
  const float* bo    = (const float*)d_in[7];
  const float* pg    = (const float*)d_in[8];
  const float* pb    = (const float*)d_in[9];

  char* ws = (char*)d_ws;
  u16*   wbf    = (u16*)ws;
  float* statsf = (float*)(ws + WS_STATS);
  u8*    qg     = (u8*)(ws + WS_Q);
  u8*    kg     = (u8*)(ws + WS_K);
  u8*    vtp    = (u8*)(ws + WS_V);
  float* outp   = (float*)d_out;

  k_init<<<4096, 256, 0, stream>>>(wq, wk, wv, wo, wbf, statsf);
  k_xstats<<<248, 512, 0, stream>>>(x, statsf);
  k_finalize_ch<<<1, 512, 0, stream>>>(gamma, beta, statsf);
  k_qkv<<<1024, 512, 0, stream>>>(x, wbf, statsf, qg, kg, vtp);
  k_energy<<<4096, 512, 0, stream>>>(qg, kg);
  k_estats<<<256, 256, 0, stream>>>((const u16*)qg, statsf);
  k_finalize_e<<<1, 1024, 0, stream>>>(pg, pb, statsf);
  k_oproj<<<1024, 512, 0, stream>>>(x, wbf, statsf, (const u16*)qg, vtp, bo, outp);
}